// Round 10
// baseline (234.848 us; speedup 1.0000x reference)
//
#include <hip/hip_runtime.h>
#include <hip/hip_bf16.h>

namespace {

typedef unsigned short ushort;
constexpr int B  = 128;
constexpr int T  = 200;
constexpr int D  = 256;
constexpr int H  = 4;
constexpr int NE = 4;
constexpr int NL = 2;
constexpr int HD = 64;
constexpr int BT = B * T;

constexpr int BM = 64;
constexpr int BK = 64;                  // bf16 K-step (128B rows)
constexpr int MT = (T + BM - 1) / BM;   // 4 M-tiles (qkv)
constexpr int PBM = 112;                // postattn M-tile
constexpr int PMT = 2;                  // postattn M-tiles (grid = B*2 = 256)

typedef __bf16 bf16x8 __attribute__((ext_vector_type(8)));
typedef float f32x4 __attribute__((ext_vector_type(4)));
typedef unsigned short ushort8v __attribute__((ext_vector_type(8)));

__device__ inline float wave_sum(float x) {
#pragma unroll
  for (int off = 32; off > 0; off >>= 1) x += __shfl_xor(x, off);
  return x;
}
__device__ inline unsigned int f2bf(float x) {  // RNE bf16 (as uint)
  unsigned int u = __float_as_uint(x);
  return (u + 0x7fffu + ((u >> 16) & 1u)) >> 16;
}
__device__ inline ushort f2bfs(float x) { return (ushort)f2bf(x); }
__device__ inline float bf2f(ushort u) {
  return __uint_as_float((unsigned int)u << 16);
}
__device__ inline bf16x8 ldb8(const ushort* p) {
  return __builtin_bit_cast(bf16x8, *(const ushort8v*)p);
}

// ---------------- fp32 -> bf16 weight conversion (single launch) ------------
__global__ void k_cvt_all(const float* __restrict__ a, const float* __restrict__ b,
                          const float* __restrict__ c, const float* __restrict__ d,
                          ushort* __restrict__ dst, int nA4, int nB4, int nC4) {
  int i = blockIdx.x * 256 + threadIdx.x;
  int nAB = nA4 + nB4, nABC = nAB + nC4, tot = nABC + nC4;
  if (i >= tot) return;
  const float* src; int j;
  if (i < nA4)       { src = a; j = i; }
  else if (i < nAB)  { src = b; j = i - nA4; }
  else if (i < nABC) { src = c; j = i - nAB; }
  else               { src = d; j = i - nABC; }
  float4 v = ((const float4*)src)[j];
  ushort4 u;
  u.x = f2bfs(v.x); u.y = f2bfs(v.y); u.z = f2bfs(v.z); u.w = f2bfs(v.w);
  ((ushort4*)dst)[i] = u;
}

// ---------------- embed + attn-LN(layer0) ----------------
__global__ __launch_bounds__(256) void k_embed_ln(
    const int* __restrict__ log_seqs, const float* __restrict__ item_emb,
    const float* __restrict__ pos_emb, const float* __restrict__ lns,
    const float* __restrict__ lnb, ushort* __restrict__ seqs,
    ushort* __restrict__ qn) {
  int tok = blockIdx.x * 4 + (threadIdx.x >> 6);
  int lane = threadIdx.x & 63;
  int t = tok % T;
  int idx = log_seqs[tok];
  int pos = (idx != 0) ? (t + 1) : 0;
  float4 iv = ((const float4*)(item_emb + (size_t)idx * D))[lane];
  float4 pv = ((const float4*)(pos_emb + (size_t)pos * D))[lane];
  float v0 = iv.x * 16.0f + pv.x;
  float v1 = iv.y * 16.0f + pv.y;
  float v2 = iv.z * 16.0f + pv.z;
  float v3 = iv.w * 16.0f + pv.w;
  ushort4 r;
  r.x = f2bfs(v0); r.y = f2bfs(v1); r.z = f2bfs(v2); r.w = f2bfs(v3);
  ((ushort4*)(seqs + (size_t)tok * D))[lane] = r;
  float mean = wave_sum(v0 + v1 + v2 + v3) * (1.0f / D);
  float c0 = v0 - mean, c1 = v1 - mean, c2 = v2 - mean, c3 = v3 - mean;
  float var = wave_sum(c0 * c0 + c1 * c1 + c2 * c2 + c3 * c3) * (1.0f / D);
  float inv = rsqrtf(var + 1e-8f);
  float4 sv = ((const float4*)lns)[lane];
  float4 bv = ((const float4*)lnb)[lane];
  ushort4 o;
  o.x = f2bfs(c0 * inv * sv.x + bv.x);
  o.y = f2bfs(c1 * inv * sv.y + bv.y);
  o.z = f2bfs(c2 * inv * sv.z + bv.z);
  o.w = f2bfs(c3 * inv * sv.w + bv.w);
  ((ushort4*)(qn + (size_t)tok * D))[lane] = o;
}

// ---- bf16 tile staging with XOR bank swizzle (256-thread, [ROWS][BK]) ----
template <int ROWS>
__device__ inline void stage_bf16(const ushort* __restrict__ src, int ld,
                                  int valid, int k0, ushort* __restrict__ dst,
                                  int tid) {
#pragma unroll
  for (int p = 0; p < ROWS * 8 / 256; p++) {
    int slot = p * 256 + tid;
    int r = slot >> 3, s_st = slot & 7;
    int s_src = s_st ^ (r & 7);
    int rs = (r < valid) ? r : (valid - 1);   // clamp: finite garbage, masked later
    uint4 w = *(const uint4*)(src + (size_t)rs * ld + k0 + s_src * 8);
    *(uint4*)(dst + r * BK + s_st * 8) = w;
  }
}
__device__ inline bf16x8 frag(const ushort* tile, int row, int slot_log) {
  int s = slot_log ^ (row & 7);
  return ldb8(tile + row * BK + s * 8);
}
// [rows][256] swizzled tile helpers
__device__ inline bf16x8 frag256(const ushort* tile, int row, int k0, int slot_log) {
  int s = slot_log ^ (row & 7);
  return ldb8(tile + row * 256 + k0 + s * 8);
}
__device__ inline int swz256(int row, int col) {
  int s = ((col >> 3) & 7) ^ (row & 7);
  return row * 256 + (col & ~63) + s * 8 + (col & 7);
}
// W-tile ([256][BK slice]) reg load / LDS store (512 threads, 4 x uint4)
__device__ inline void wload(const ushort* __restrict__ w, int k0, uint4* regs,
                             int tid) {
#pragma unroll
  for (int p = 0; p < 4; p++) {
    int slot = p * 512 + tid;
    int r = slot >> 3, s = slot & 7;
    int ssrc = s ^ (r & 7);
    regs[p] = *(const uint4*)(w + (size_t)r * D + k0 + ssrc * 8);
  }
}
__device__ inline void wstore(const uint4* regs, ushort* __restrict__ dst,
                              int tid) {
#pragma unroll
  for (int p = 0; p < 4; p++) {
    int slot = p * 512 + tid;
    int r = slot >> 3, s = slot & 7;
    *(uint4*)(dst + r * BK + s * 8) = regs[p];
  }
}

// ---------------- QKV GEMM (bf16), routed expert, XCD-chunked ---------------
__global__ __launch_bounds__(256) void k_gemm_qkv(
    const ushort* __restrict__ qn, const ushort* __restrict__ seqs,
    const ushort* __restrict__ w, const float* __restrict__ bias,
    const int* __restrict__ expert_ids,
    ushort* __restrict__ q, ushort* __restrict__ k, ushort* __restrict__ v) {
  constexpr int NWG = B * MT * 6;   // 3072, %8==0
  int phys = blockIdx.x;
  int bid = (phys & 7) * (NWG >> 3) + (phys >> 3);
  int nt = bid % 6;
  int mt = (bid / 6) % MT;
  int b  = bid / (6 * MT);
  int e = expert_ids[b];
  int m0 = mt * BM;
  int valid = min(BM, T - m0);
  const ushort* X = (nt < 2) ? qn : seqs;
  const ushort* Xb = X + (size_t)(b * T + m0) * D;
  const ushort* Wb = w + (size_t)e * 3 * D * D + (size_t)nt * 128 * D;

  __shared__ __align__(16) ushort Xl[BM * BK];
  __shared__ __align__(16) ushort Wl[128 * BK];
  int tid = threadIdx.x, wv = tid >> 6, lane = tid & 63;
  int g = lane >> 4, lm = lane & 15;

  f32x4 acc[4][2];
#pragma unroll
  for (int mi = 0; mi < 4; mi++)
#pragma unroll
    for (int ni = 0; ni < 2; ni++) acc[mi][ni] = (f32x4){0.f, 0.f, 0.f, 0.f};

  for (int kt = 0; kt < D / BK; kt++) {
    stage_bf16<BM>(Xb, D, valid, kt * BK, Xl, tid);
    stage_bf16<128>(Wb, D, 128, kt * BK, Wl, tid);
    __syncthreads();
    bf16x8 a[4][2], bb[2][2];
#pragma unroll
    for (int mi = 0; mi < 4; mi++)
#pragma unroll
      for (int hh = 0; hh < 2; hh++)
        a[mi][hh] = frag(Xl, mi * 16 + lm, hh * 4 + g);
#pragma unroll
    for (int ni = 0; ni < 2; ni++)
#pragma unroll
      for (int hh = 0; hh < 2; hh++)
        bb[ni][hh] = frag(Wl, wv * 32 + ni * 16 + lm, hh * 4 + g);
#pragma unroll
    for (int mi = 0; mi < 4; mi++)
#pragma unroll
      for (int ni = 0; ni < 2; ni++) {
        acc[mi][ni] = __builtin_amdgcn_mfma_f32_16x16x32_bf16(a[mi][0], bb[ni][0],
                                                              acc[mi][ni], 0, 0, 0);
        acc[mi][ni] = __builtin_amdgcn_mfma_f32_16x16x32_bf16(a[mi][1], bb[ni][1],
                                                              acc[mi][ni], 0, 0, 0);
      }
    __syncthreads();
  }

  ushort* outb = (nt < 2) ? q : (nt < 4 ? k : v);
  size_t rowbase = (size_t)(b * T + m0);
#pragma unroll
  for (int mi = 0; mi < 4; mi++) {
#pragma unroll
    for (int ni = 0; ni < 2; ni++) {
      int col = (nt & 1) * 128 + wv * 32 + ni * 16 + lm;
      float bbv = bias[e * 3 * D + nt * 128 + wv * 32 + ni * 16 + lm];
#pragma unroll
      for (int r = 0; r < 4; r++) {
        int lr = mi * 16 + 4 * g + r;
        if (lr < valid)
          outb[(rowbase + lr) * D + col] = f2bfs(acc[mi][ni][r] + bbv);
      }
    }
  }
}

// ---------------- fused post-attention, BM=112 (grid = 256 = 1 block/CU) ----
// oproj+res+LN -> FFN1 -> FFN2+res+LN; xn and h never leave LDS.
// 8 waves = 4M x 2N; per wave 32 rows x 128 cols (acc[2][8]).
__global__ __launch_bounds__(512, 2) void k_postattn(
    const ushort* __restrict__ o, const ushort* __restrict__ qn,
    const ushort* __restrict__ wo, const float* __restrict__ bo,
    const float* __restrict__ lns1, const float* __restrict__ lnb1,
    const ushort* __restrict__ w1, const float* __restrict__ b1,
    const ushort* __restrict__ w2, const float* __restrict__ b2,
    const float* __restrict__ lns2, const float* __restrict__ lnb2,
    const int* __restrict__ expert_ids,
    ushort* __restrict__ seqs, ushort* __restrict__ qno) {
  int bid = blockIdx.x;
  int mt = bid & 1;
  int b  = bid >> 1;
  int e = expert_ids[b];
  int m0 = mt * PBM;
  int valid = min(PBM, T - m0);          // 112 or 88
  size_t rowbase = (size_t)(b * T + m0);
  const ushort* Ob = o + rowbase * D;
  const ushort* We = wo + (size_t)e * D * D;

  __shared__ __align__(16) ushort U[PBM * 256];    // 57344B: O tile, then h
  __shared__ __align__(16) ushort XnL[PBM * 256];  // 57344B: fwd-LN output
  __shared__ __align__(16) ushort Wl[D * BK];      // 32768B: W tile
  __shared__ float rs_sum[PBM][2];
  __shared__ float rs_sq[PBM][2];

  int tid = threadIdx.x, wv = tid >> 6, lane = tid & 63;
  int wr = wv >> 1, wc = wv & 1;         // 4 M-groups x 2 N-groups
  int g = lane >> 4, lm = lane & 15;

  f32x4 acc[2][8];
#pragma unroll
  for (int mi = 0; mi < 2; mi++)
#pragma unroll
    for (int ni = 0; ni < 8; ni++) acc[mi][ni] = (f32x4){0.f, 0.f, 0.f, 0.f};

  uint4 wreg[4];
  wload(We, 0, wreg, tid);               // W tile 0 in regs
  // stage O -> U (once): 112*32 = 3584 uint4 slots, 7 per thread
#pragma unroll
  for (int p = 0; p < 7; p++) {
    int i = p * 512 + tid;
    int r = i >> 5, s = i & 31;
    int k0 = (s >> 3) * 64, sl = s & 7;
    int rs = (r < valid) ? r : (valid - 1);
    uint4 w = *(const uint4*)(Ob + (size_t)rs * D + k0 + sl * 8);
    *(uint4*)(U + r * 256 + k0 + ((sl ^ (r & 7))) * 8) = w;
  }

  // ---- macro-ish GEMM phase: A (LDS 256-wide tile), W chain ----
#define PA_GEMM(ABUF, WSRC, NSRC)                                              \
  for (int kt = 0; kt < 4; kt++) {                                             \
    wstore(wreg, Wl, tid);                                                     \
    __syncthreads();                                                           \
    if (kt < 3) wload(WSRC, (kt + 1) * BK, wreg, tid);                         \
    else if (NSRC) wload((const ushort*)(NSRC), 0, wreg, tid);                 \
    bf16x8 a[2][2], bbv[8][2];                                                 \
    _Pragma("unroll") for (int mi = 0; mi < 2; mi++)                           \
      _Pragma("unroll") for (int hh = 0; hh < 2; hh++) {                       \
        int rowa = wr * 32 + mi * 16 + lm;                                     \
        rowa = (rowa < PBM) ? rowa : (PBM - 1);                                \
        a[mi][hh] = frag256(ABUF, rowa, kt * BK, hh * 4 + g);                  \
      }                                                                        \
    _Pragma("unroll") for (int ni = 0; ni < 8; ni++)                           \
      _Pragma("unroll") for (int hh = 0; hh < 2; hh++)                         \
        bbv[ni][hh] = frag(Wl, wc * 128 + ni * 16 + lm, hh * 4 + g);           \
    _Pragma("unroll") for (int mi = 0; mi < 2; mi++)                           \
      _Pragma("unroll") for (int ni = 0; ni < 8; ni++) {                       \
        acc[mi][ni] = __builtin_amdgcn_mfma_f32_16x16x32_bf16(                 \
            a[mi][0], bbv[ni][0], acc[mi][ni], 0, 0, 0);                       \
        acc[mi][ni] = __builtin_amdgcn_mfma_f32_16x16x32_bf16(                 \
            a[mi][1], bbv[ni][1], acc[mi][ni], 0, 0, 0);                       \
      }                                                                        \
    __syncthreads();                                                           \
  }

  __syncthreads();   // U staged, Wl safe to write

  // ================= phase 1: oproj GEMM (A = U) ============================
  PA_GEMM(U, We, w1)
  // epilogue 1: + bias + qn residual, row stats, fwd-LN -> XnL
#pragma unroll
  for (int ni = 0; ni < 8; ni++) {
    int col = wc * 128 + ni * 16 + lm;
    float bbv = bo[e * D + col];
#pragma unroll
    for (int mi = 0; mi < 2; mi++)
#pragma unroll
      for (int r = 0; r < 4; r++) {
        int lr = wr * 32 + mi * 16 + 4 * g + r;
        int lrc = (lr < valid) ? lr : (valid - 1);
        acc[mi][ni][r] += bbv + bf2f(qn[(rowbase + lrc) * D + col]);
      }
  }
#pragma unroll
  for (int mi = 0; mi < 2; mi++)
#pragma unroll
    for (int r = 0; r < 4; r++) {
      float s = 0.f, q2 = 0.f;
#pragma unroll
      for (int ni = 0; ni < 8; ni++) {
        float x = acc[mi][ni][r];
        s += x; q2 += x * x;
      }
#pragma unroll
      for (int off = 1; off < 16; off <<= 1) {
        s += __shfl_xor(s, off);
        q2 += __shfl_xor(q2, off);
      }
      int row = wr * 32 + mi * 16 + 4 * g + r;
      if (lm == 0 && row < PBM) {
        rs_sum[row][wc] = s;
        rs_sq[row][wc] = q2;
      }
    }
  __syncthreads();
  {
    float scv[8], bcv[8];
#pragma unroll
    for (int ni = 0; ni < 8; ni++) {
      int col = wc * 128 + ni * 16 + lm;
      scv[ni] = lns1[col];
      bcv[ni] = lnb1[col];
    }
#pragma unroll
    for (int mi = 0; mi < 2; mi++)
#pragma unroll
      for (int r = 0; r < 4; r++) {
        int lr = wr * 32 + mi * 16 + 4 * g + r;
        int lrc = (lr < PBM) ? lr : (PBM - 1);
        float2 s2 = *(const float2*)rs_sum[lrc];
        float2 q2v = *(const float2*)rs_sq[lrc];
        float mean = (s2.x + s2.y) * (1.0f / D);
        float var = (q2v.x + q2v.y) * (1.0f / D) - mean * mean;
        float rstd = rsqrtf(fmaxf(var, 0.f) + 1e-8f);
        if (lr < PBM) {
#pragma unroll
          for (int ni = 0; ni < 8; ni++) {
            int col = wc * 128 + ni * 16 + lm;
            float xn = (acc[mi][ni][r] - mean) * rstd * scv[ni] + bcv[ni];
            XnL[swz256(lr, col)] = f2bfs(xn);
          }
        }
      }
  }
  __syncthreads();   // XnL visible

  // ================= phase 2: FFN1 (A = XnL; h -> U) ========================
#pragma unroll
  for (int mi = 0; mi < 2; mi++)
#pragma unroll
    for (int ni = 0; ni < 8; ni++) acc[mi][ni] = (f32x4){0.f, 0.f, 0.f, 0.f};
  PA_GEMM(XnL, w1, w2)
  // epilogue 2: h = relu(acc + b1) -> U (O data dead)
#pragma unroll
  for (int ni = 0; ni < 8; ni++) {
    int col = wc * 128 + ni * 16 + lm;
    float bbv = b1[col];
#pragma unroll
    for (int mi = 0; mi < 2; mi++)
#pragma unroll
      for (int r = 0; r < 4; r++) {
        int row = wr * 32 + mi * 16 + 4 * g + r;
        if (row < PBM)
          U[swz256(row, col)] = f2bfs(fmaxf(acc[mi][ni][r] + bbv, 0.f));
      }
  }
  __syncthreads();   // h visible

  // ================= phase 3: FFN2 (A = U = h) ==============================
#pragma unroll
  for (int mi = 0; mi < 2; mi++)
#pragma unroll
    for (int ni = 0; ni < 8; ni++) acc[mi][ni] = (f32x4){0.f, 0.f, 0.f, 0.f};
  PA_GEMM(U, w2, (const ushort*)nullptr)
  // epilogue 3: + b2 + xn residual, row stats, next-layer attn-LN
#pragma unroll
  for (int ni = 0; ni < 8; ni++) {
    int col = wc * 128 + ni * 16 + lm;
    float bbv = b2[col];
#pragma unroll
    for (int mi = 0; mi < 2; mi++)
#pragma unroll
      for (int r = 0; r < 4; r++) {
        int row = wr * 32 + mi * 16 + 4 * g + r;
        int rowc = (row < PBM) ? row : (PBM - 1);
        acc[mi][ni][r] += bbv + bf2f(XnL[swz256(rowc, col)]);
      }
  }
#pragma unroll
  for (int mi = 0; mi < 2; mi++)
#pragma unroll
    for (int r = 0; r < 4; r++) {
      float s = 0.f, q2 = 0.f;
#pragma unroll
      for (int ni = 0; ni < 8; ni++) {
        float x = acc[mi][ni][r];
        s += x; q2 += x * x;
      }
#pragma unroll
      for (int off = 1; off < 16; off <<= 1) {
        s += __shfl_xor(s, off);
        q2 += __shfl_xor(q2, off);
      }
      int row = wr * 32 + mi * 16 + 4 * g + r;
      if (lm == 0 && row < PBM) {
        rs_sum[row][wc] = s;
        rs_sq[row][wc] = q2;
      }
    }
  __syncthreads();
  {
    float scv[8], bcv[8];
#pragma unroll
    for (int ni = 0; ni < 8; ni++) {
      int col = wc * 128 + ni * 16 + lm;
      scv[ni] = lns2[col];
      bcv[ni] = lnb2[col];
    }
#pragma unroll
    for (int mi = 0; mi < 2; mi++)
#pragma unroll
      for (int r = 0; r < 4; r++) {
        int lr = wr * 32 + mi * 16 + 4 * g + r;
        int lrc = (lr < PBM) ? lr : (PBM - 1);
        float2 s2 = *(const float2*)rs_sum[lrc];
        float2 q2v = *(const float2*)rs_sq[lrc];
        float mean = (s2.x + s2.y) * (1.0f / D);
        float var = (q2v.x + q2v.y) * (1.0f / D) - mean * mean;
        float rstd = rsqrtf(fmaxf(var, 0.f) + 1e-8f);
        if (lr < valid) {
#pragma unroll
          for (int ni = 0; ni < 8; ni++) {
            int col = wc * 128 + ni * 16 + lm;
            float val = acc[mi][ni][r];
            size_t idx = (rowbase + lr) * D + col;
            seqs[idx] = f2bfs(val);
            qno[idx] = f2bfs((val - mean) * rstd * scv[ni] + bcv[ni]);
          }
        }
      }
  }
#undef PA_GEMM
}

// ---------------- MFMA flash attention (bf16 io) -----------------------------
constexpr int KROWS = 224;
constexpr int KSS = 72;
constexpr int VSS = 232;
constexpr int PSS = 40;
__global__ __launch_bounds__(256) void k_attn(const ushort* __restrict__ q,
                                              const ushort* __restrict__ k,
                                              const ushort* __restrict__ v,
                                              ushort* __restrict__ o) {
  int bh = blockIdx.x;
  int b = bh >> 2, h = bh & 3;
  __shared__ __align__(16) ushort Kl[KROWS][KSS];
  __shared__ __align__(16) ushort Vt[HD][VSS];
  __shared__ __align__(16) ushort Pl[4][16][PSS];
  const size_t base = (size_t)b * T * D + h * HD;
  int tid = threadIdx.x, wave = tid >> 6, lane = tid & 63;
  int g = lane >> 4, lm = lane & 15;

#pragma unroll
  for (int p = 0; p < 7; p++) {
    int slot = p * 256 + tid;
    int key = slot >> 3, s8 = (slot & 7) << 3;
    uint4 w = make_uint4(0, 0, 0, 0);
    if (key < T) w = *(const uint4*)(k + base + (size_t)key * D + s8);
    *(uint4*)&Kl[key][s8] = w;
  }
#pragma unroll
  for (int p = 0; p < 28; p++) {
    int slot = p * 256 + tid;
    int key = slot >> 5, dp = (slot & 31) << 1;
    unsigned int w = 0;
    if (key < T) w = *(const unsigned int*)(v + base + (size_t)key * D + dp);
    Vt[dp][key] = (ushort)(w & 0xffffu);
    Vt[dp + 1][key] = (ushort)(w >> 16);
  }
  __syncthreads();

  const unsigned long long SCHED = 0x0189D27AD36BD45CULL;
  unsigned sch = (unsigned)(SCHED >> (wave * 16)) & 0xFFFFu;
  const float sc = 0.125f * 1.44269504f;

  for (int si = 0; si < 4; si++) {
    int qt = (sch >> (si * 4)) & 15;
    if (qt > 12) break;
    int row = qt * 16 + lm;
    int qrow = min(row, T - 1);
    const ushort* qr = q + base + (size_t)qrow * D;
    bf16x8 qf0 = ldb8(qr + 8 * g);
    bf16x8 qf1 = ldb8(qr + 32 + 8 * g);

    f32x4 oacc[4];
#pragma unroll
    for (int dt = 0; dt < 4; dt++) oacc[dt] = (f32x4){0.f, 0.f, 0.f, 0.f};
    float mrun = -3e38f, lsum = 0.f;

    int nch = qt / 2 + 1;
    for (int c = 0; c < nch; c++) {
      int kb = c * 32;
      f32x4 s01[2];
#pragma unroll
      for (int t = 0; t < 2; t++) {
        int krow = kb + t * 16 + lm;
        bf16x8 a0 = ldb8(&Kl[krow][8 * g]);
        bf16x8 a1 = ldb8(&Kl[krow][32 + 8 * g]);
        f32x4 z = (f32x4){0.f, 0.f, 0.f, 0.f};
        z = __builtin_amdgcn_mfma_f32_16x16x32_bf16(a0, qf0, z, 0, 0, 0);
        z = __builtin_amdgcn_mfma_f32_16x16x32_bf16(a1, qf1, z, 0, 0, 0);
        s01[t] = z;
      }
      float sv[8];
      float mx = -3e38f;
#pragma unroll
      for (int t = 0; t < 2; t++)
#pragma unroll
        for (int r = 0; r < 4; r++) {
          int key = kb + t * 16 + 4 * g + r;
          float x = (key <= row) ? s01[t][r] * sc : -3e38f;
          sv[t * 4 + r] = x;
          mx = fmaxf(mx, x);
        }
      mx = fmaxf(mx, __shfl_xor(mx, 16));
      mx = fmaxf(mx, __shfl_xor(mx, 32));
      float mnew = fmaxf(mrun, mx);
      float corr = __builtin_amdgcn_exp2f(mrun - mnew);
      float ps = 0.f;
      ushort8v pu;
#pragma unroll
      for (int i = 0; i < 8; i++) {
        float p = __builtin_amdgcn_exp2f(sv[i] - mnew);
        ps += p;
        pu[i] = f2bfs(p);
      }
      ps += __shfl_xor(ps, 16);
      ps += __shfl_xor(ps, 32);
      lsum = lsum * corr + ps;
      mrun = mnew;
      *(ushort4*)&Pl[wave][lm][4 * g]      = ((ushort4*)&pu)[0];
      *(ushort4*)&Pl[wave][lm][16 + 4 * g] = ((ushort4*)&pu)[1];
#pragma unroll
      for (int dt = 0; dt < 4; dt++)
#pragma unroll
        for (int r = 0; r < 4; r++) oacc[dt][r] *= corr;
      bf16x8 pf = ldb8(&Pl[wave][lm][8 * g]);
#pragma unroll
      for (int dt = 0; dt < 4; dt++) {
        bf16x8 av = ldb8(&Vt[dt * 16 + lm][kb + 8 * g]);
        oacc[dt] = __builtin_amdgcn_mfma_f32_16x16x32_bf16(av, pf, oacc[dt], 0, 0, 0);
      }
    }

    if (row < T) {
      float rinv = 1.0f / lsum;
      ushort* orow = o + base + (size_t)row * D;
#pragma unroll
      for (int dt = 0; dt < 4; dt++) {
        ushort4 uo;
        uo.x = f2bfs(oacc[dt][0] * rinv);
        uo.y = f2bfs(oacc[dt][1] * rinv);
        uo.z = f2bfs(oacc[dt][2] * rinv);
        uo.w = f2bfs(oacc[dt][3] * rinv);
        *(ushort4*)(orow + dt * 16 + 4 * g) = uo;
      }
    }
  }
}

// ---------------- final LN + pos/neg logits ----------------------------------
__global__ __launch_bounds__(256) void k_final(const ushort* __restrict__ seqs,
                                               const float* __restrict__ sc,
                                               const float* __restrict__ bi,
                                               const int* __restrict__ pos_seqs,
                                               const int* __restrict__ neg_seqs,
                                               const float* __restrict__ item_emb,
                                               float* __restrict__ out) {
  int tok = blockIdx.x * 4 + (threadIdx.x >> 6);
  int lane = threadIdx.x & 63;
  ushort4 xu = ((const ushort4*)(seqs + (size_t)tok * D))[lane];
  float x0 = bf2f(xu.x), x1 = bf2f(xu.y), x2 = bf2f(xu.z), x3 = bf2f(xu.w);
  float mean = wave_sum(x0 + x1 + x2 + x3) * (1.0f / D);
  float c0 = x0 - mean, c1 = x1 - mean, c2 = x2 - mean, c3 = x3 - mean;
  float var = wave_sum(c0 * c0 + c1 * c1 + c2 * c2 + c3 * c3) * (1.0f / D);
  float inv = rsqrtf(var + 1e-8f);
  float4 sv = ((const float4*)sc)[lane];
  float4 bv = ((const float4*)bi)[lane];
  float f0 = c0 * inv * sv.x + bv.x;
  float f1 = c1 * inv * sv.y + bv.y;
  float f2 = c2 * inv * sv.z + bv.z;
  float f3 = c3 * inv * sv.w + bv.w;
  int ip = pos_seqs[tok];
  int in_ = neg_seqs[tok];
  float4 pe = ((const float4*)(item_emb + (size_t)ip * D))[lane];
  float4 ne = ((const float4*)(item_emb + (size_t)in_ * D))[lane];
  float dp = wave_sum(f0 * pe.x + f1 * pe.y + f2 * pe.z + f3 * pe.w);
  float dn = wave_sum(f0 * ne.x + f1 * ne.y + f2 * ne.z + f3 * ne.w);
  if (lane == 0) {
    out[tok] = dp;
    out[BT + tok] = dn;
  }
}

}  // namespace

extern "C" void kernel_launch(void* const* d_in, const int* in_sizes, int n_in,
                              void* d_out, int out_size, void* d_ws, size_t ws_size,
                              hipStream_t stream) {
  const int*   log_seqs   = (const int*)d_in[0];
  const int*   pos_seqs   = (const int*)d_in[1];
  const int*   neg_seqs   = (const int*)d_in[2];
  const int*   expert_ids = (const int*)d_in[3];
  const float* item_emb   = (const float*)d_in[4];
  const float* pos_emb    = (const float*)d_in[5];
  const float* attn_ln_s  = (const float*)d_in[6];
  const float* attn_ln_b  = (const float*)d_in[7];
  const float* in_w       = (const float*)d_in[8];
  const float* in_b       = (const float*)d_in[9];
  const float* out_w      = (const float*)d_in[10];
  const float* out_b      = (const float*)d_in[11];
  const float* fwd_ln_s   = (const float*)d_in[12];
  const float* fwd_ln_b   = (const float*)d_in[13];
  const float* ffn_w1     = (const float*)d_in[14];
  const float* ffn_b1     = (const float*)d_in[15];
  const float* ffn_w2     = (const float*)d_in[16];
  const float* ffn_b2     = (const float*)d_in[17];
  const float* last_ln_s  = (const float*)d_in[18];
  const float* last_ln_b  = (const float*)d_in[19];
  float* out = (float*)d_out;

  const size_t N = (size_t)BT * D;
  ushort* seqs = (ushort*)d_ws;
  ushort* qn   = seqs + N;
  ushort* q    = qn + N;
  ushort* kbuf = q + N;
  ushort* vbuf = kbuf + N;
  ushort* obuf = kbuf;   // alias: attn stages K to LDS before writing o
  ushort* wqkv = vbuf + N;                               // [NL][NE][3D][D]
  ushort* wout = wqkv + (size_t)NL * NE * 3 * D * D;     // [NL][NE][D][D]
  ushort* wf1  = wout + (size_t)NL * NE * D * D;         // [NL][D][D]
  ushort* wf2  = wf1 + (size_t)NL * D * D;               // [NL][D][D]

  {
    int nA4 = NL * NE * 3 * D * D / 4;
    int nB4 = NL * NE * D * D / 4;
    int nC4 = NL * D * D / 4;
    int tot = nA4 + nB4 + 2 * nC4;
    k_cvt_all<<<(tot + 255) / 256, 256, 0, stream>>>(in_w, out_w, ffn_w1, ffn_w2,
                                                     wqkv, nA4, nB4, nC4);
  }

  k_embed_ln<<<BT / 4, 256, 0, stream>>>(log_seqs, item_emb, pos_emb,
                                         attn_ln_s, attn_ln_b, seqs, qn);

  for (int l = 0; l < NL; l++) {
    int ln_next = (l + 1 < NL) ? (l + 1) : l;   // last-layer qn write unused
    k_gemm_qkv<<<B * MT * 6, 256, 0, stream>>>(
        qn, seqs, wqkv + (size_t)l * NE * 3 * D * D,
        in_b + (size_t)l * NE * 3 * D, expert_ids, q, kbuf, vbuf);
    k_attn<<<B * H, 256, 0, stream>>>(q, kbuf, vbuf, obuf);
    k_postattn<<<B * PMT, 512, 0, stream>>>(
        obuf, qn, wout + (size_t)l * NE * D * D, out_b + (size_t)l * NE * D,
        fwd_ln_s + (size_t)l * D, fwd_ln_b + (size_t)l * D,
        wf1 + (size_t)l * D * D, ffn_b1 + (size_t)l * D,
        wf2 + (size_t)l * D * D, ffn_b2 + (size_t)l * D,
        attn_ln_s + (size_t)ln_next * D, attn_ln_b + (size_t)ln_next * D,
        expert_ids, seqs, qn);
  }

  k_final<<<BT / 4, 256, 0, stream>>>(seqs, last_ln_s, last_ln_b, pos_seqs,
                                      neg_seqs, item_emb, out);
}

// Round 11
// 216.779 us; speedup vs baseline: 1.0834x; 1.0834x over previous
//
#include <hip/hip_runtime.h>
#include <hip/hip_bf16.h>

namespace {

typedef unsigned short ushort;
constexpr int B  = 128;
constexpr int T  = 200;
constexpr int D  = 256;
constexpr int H  = 4;
constexpr int NE = 4;
constexpr int NL = 2;
constexpr int HD = 64;
constexpr int BT = B * T;

constexpr int BM = 64;
constexpr int BK = 64;                  // bf16 K-step (128B rows)
constexpr int MT = (T + BM - 1) / BM;   // 4 M-tiles

typedef __bf16 bf16x8 __attribute__((ext_vector_type(8)));
typedef float f32x4 __attribute__((ext_vector_type(4)));
typedef unsigned short ushort8v __attribute__((ext_vector_type(8)));

__device__ inline float wave_sum(float x) {
#pragma unroll
  for (int off = 32; off > 0; off >>= 1) x += __shfl_xor(x, off);
  return x;
}
__device__ inline unsigned int f2bf(float x) {  // RNE bf16 (as uint)
  unsigned int u = __float_as_uint(x);
  return (u + 0x7fffu + ((u >> 16) & 1u)) >> 16;
}
__device__ inline ushort f2bfs(float x) { return (ushort)f2bf(x); }
__device__ inline float bf2f(ushort u) {
  return __uint_as_float((unsigned int)u << 16);
}
__device__ inline bf16x8 ldb8(const ushort* p) {
  return __builtin_bit_cast(bf16x8, *(const ushort8v*)p);
}

// ---------------- fp32 -> bf16 weight conversion (single launch) ------------
__global__ void k_cvt_all(const float* __restrict__ a, const float* __restrict__ b,
                          const float* __restrict__ c, const float* __restrict__ d,
                          ushort* __restrict__ dst, int nA4, int nB4, int nC4) {
  int i = blockIdx.x * 256 + threadIdx.x;
  int nAB = nA4 + nB4, nABC = nAB + nC4, tot = nABC + nC4;
  if (i >= tot) return;
  const float* src; int j;
  if (i < nA4)       { src = a; j = i; }
  else if (i < nAB)  { src = b; j = i - nA4; }
  else if (i < nABC) { src = c; j = i - nAB; }
  else               { src = d; j = i - nABC; }
  float4 v = ((const float4*)src)[j];
  ushort4 u;
  u.x = f2bfs(v.x); u.y = f2bfs(v.y); u.z = f2bfs(v.z); u.w = f2bfs(v.w);
  ((ushort4*)dst)[i] = u;
}

// ---------------- embed + attn-LN(layer0) ----------------
__global__ __launch_bounds__(256) void k_embed_ln(
    const int* __restrict__ log_seqs, const float* __restrict__ item_emb,
    const float* __restrict__ pos_emb, const float* __restrict__ lns,
    const float* __restrict__ lnb, ushort* __restrict__ seqs,
    ushort* __restrict__ qn) {
  int tok = blockIdx.x * 4 + (threadIdx.x >> 6);
  int lane = threadIdx.x & 63;
  int t = tok % T;
  int idx = log_seqs[tok];
  int pos = (idx != 0) ? (t + 1) : 0;
  float4 iv = ((const float4*)(item_emb + (size_t)idx * D))[lane];
  float4 pv = ((const float4*)(pos_emb + (size_t)pos * D))[lane];
  float v0 = iv.x * 16.0f + pv.x;
  float v1 = iv.y * 16.0f + pv.y;
  float v2 = iv.z * 16.0f + pv.z;
  float v3 = iv.w * 16.0f + pv.w;
  ushort4 r;
  r.x = f2bfs(v0); r.y = f2bfs(v1); r.z = f2bfs(v2); r.w = f2bfs(v3);
  ((ushort4*)(seqs + (size_t)tok * D))[lane] = r;
  float mean = wave_sum(v0 + v1 + v2 + v3) * (1.0f / D);
  float c0 = v0 - mean, c1 = v1 - mean, c2 = v2 - mean, c3 = v3 - mean;
  float var = wave_sum(c0 * c0 + c1 * c1 + c2 * c2 + c3 * c3) * (1.0f / D);
  float inv = rsqrtf(var + 1e-8f);
  float4 sv = ((const float4*)lns)[lane];
  float4 bv = ((const float4*)lnb)[lane];
  ushort4 o;
  o.x = f2bfs(c0 * inv * sv.x + bv.x);
  o.y = f2bfs(c1 * inv * sv.y + bv.y);
  o.z = f2bfs(c2 * inv * sv.z + bv.z);
  o.w = f2bfs(c3 * inv * sv.w + bv.w);
  ((ushort4*)(qn + (size_t)tok * D))[lane] = o;
}

// ---- bf16 tile staging with XOR bank swizzle (256-thread, [ROWS][BK]) ----
template <int ROWS>
__device__ inline void stage_bf16(const ushort* __restrict__ src, int ld,
                                  int valid, int k0, ushort* __restrict__ dst,
                                  int tid) {
#pragma unroll
  for (int p = 0; p < ROWS * 8 / 256; p++) {
    int slot = p * 256 + tid;
    int r = slot >> 3, s_st = slot & 7;
    int s_src = s_st ^ (r & 7);
    int rs = (r < valid) ? r : (valid - 1);   // clamp: finite garbage, masked later
    uint4 w = *(const uint4*)(src + (size_t)rs * ld + k0 + s_src * 8);
    *(uint4*)(dst + r * BK + s_st * 8) = w;
  }
}
// 512-thread variant
template <int ROWS>
__device__ inline void stage512(const ushort* __restrict__ src, int ld,
                                int valid, int k0, ushort* __restrict__ dst,
                                int tid) {
#pragma unroll
  for (int p = 0; p < ROWS * 8 / 512; p++) {
    int slot = p * 512 + tid;
    int r = slot >> 3, s_st = slot & 7;
    int s_src = s_st ^ (r & 7);
    int rs = (r < valid) ? r : (valid - 1);
    uint4 w = *(const uint4*)(src + (size_t)rs * ld + k0 + s_src * 8);
    *(uint4*)(dst + r * BK + s_st * 8) = w;
  }
}
__device__ inline bf16x8 frag(const ushort* tile, int row, int slot_log) {
  int s = slot_log ^ (row & 7);
  return ldb8(tile + row * BK + s * 8);
}
// [64][256] swizzled tile helpers
__device__ inline bf16x8 frag256(const ushort* tile, int row, int k0, int slot_log) {
  int s = slot_log ^ (row & 7);
  return ldb8(tile + row * 256 + k0 + s * 8);
}
__device__ inline int swz256(int row, int col) {
  int s = ((col >> 3) & 7) ^ (row & 7);
  return row * 256 + (col & ~63) + s * 8 + (col & 7);
}
// stage full [64][256] tile (512 threads, 4 x uint4 each)
__device__ inline void stage_full(const ushort* __restrict__ src, int ld,
                                  int valid, ushort* __restrict__ dst, int tid) {
#pragma unroll
  for (int p = 0; p < 4; p++) {
    int i = p * 512 + tid;
    int r = i >> 5, s = i & 31;
    int k0 = (s >> 3) * 64, sl = s & 7;
    int rs = (r < valid) ? r : (valid - 1);
    uint4 w = *(const uint4*)(src + (size_t)rs * ld + k0 + sl * 8);
    *(uint4*)(dst + r * 256 + k0 + ((sl ^ (r & 7))) * 8) = w;
  }
}

// ---------------- QKV GEMM (bf16), routed expert, XCD-chunked ---------------
__global__ __launch_bounds__(256) void k_gemm_qkv(
    const ushort* __restrict__ qn, const ushort* __restrict__ seqs,
    const ushort* __restrict__ w, const float* __restrict__ bias,
    const int* __restrict__ expert_ids,
    ushort* __restrict__ q, ushort* __restrict__ k, ushort* __restrict__ v) {
  constexpr int NWG = B * MT * 6;   // 3072, %8==0
  int phys = blockIdx.x;
  int bid = (phys & 7) * (NWG >> 3) + (phys >> 3);
  int nt = bid % 6;
  int mt = (bid / 6) % MT;
  int b  = bid / (6 * MT);
  int e = expert_ids[b];
  int m0 = mt * BM;
  int valid = min(BM, T - m0);
  const ushort* X = (nt < 2) ? qn : seqs;
  const ushort* Xb = X + (size_t)(b * T + m0) * D;
  const ushort* Wb = w + (size_t)e * 3 * D * D + (size_t)nt * 128 * D;

  __shared__ __align__(16) ushort Xl[BM * BK];
  __shared__ __align__(16) ushort Wl[128 * BK];
  int tid = threadIdx.x, wv = tid >> 6, lane = tid & 63;
  int g = lane >> 4, lm = lane & 15;

  f32x4 acc[4][2];
#pragma unroll
  for (int mi = 0; mi < 4; mi++)
#pragma unroll
    for (int ni = 0; ni < 2; ni++) acc[mi][ni] = (f32x4){0.f, 0.f, 0.f, 0.f};

  for (int kt = 0; kt < D / BK; kt++) {
    stage_bf16<BM>(Xb, D, valid, kt * BK, Xl, tid);
    stage_bf16<128>(Wb, D, 128, kt * BK, Wl, tid);
    __syncthreads();
    bf16x8 a[4][2], bb[2][2];
#pragma unroll
    for (int mi = 0; mi < 4; mi++)
#pragma unroll
      for (int hh = 0; hh < 2; hh++)
        a[mi][hh] = frag(Xl, mi * 16 + lm, hh * 4 + g);
#pragma unroll
    for (int ni = 0; ni < 2; ni++)
#pragma unroll
      for (int hh = 0; hh < 2; hh++)
        bb[ni][hh] = frag(Wl, wv * 32 + ni * 16 + lm, hh * 4 + g);
#pragma unroll
    for (int mi = 0; mi < 4; mi++)
#pragma unroll
      for (int ni = 0; ni < 2; ni++) {
        acc[mi][ni] = __builtin_amdgcn_mfma_f32_16x16x32_bf16(a[mi][0], bb[ni][0],
                                                              acc[mi][ni], 0, 0, 0);
        acc[mi][ni] = __builtin_amdgcn_mfma_f32_16x16x32_bf16(a[mi][1], bb[ni][1],
                                                              acc[mi][ni], 0, 0, 0);
      }
    __syncthreads();
  }

  ushort* outb = (nt < 2) ? q : (nt < 4 ? k : v);
  size_t rowbase = (size_t)(b * T + m0);
#pragma unroll
  for (int mi = 0; mi < 4; mi++) {
#pragma unroll
    for (int ni = 0; ni < 2; ni++) {
      int col = (nt & 1) * 128 + wv * 32 + ni * 16 + lm;
      float bbv = bias[e * 3 * D + nt * 128 + wv * 32 + ni * 16 + lm];
#pragma unroll
      for (int r = 0; r < 4; r++) {
        int lr = mi * 16 + 4 * g + r;
        if (lr < valid)
          outb[(rowbase + lr) * D + col] = f2bfs(acc[mi][ni][r] + bbv);
      }
    }
  }
}

// ---------------- fused post-attention, 66KB LDS -> 2 blocks/CU -------------
// oproj+res+LN -> FFN1 -> FFN2+res+LN; U reused O -> xn -> h; xn residual
// kept packed-bf16 in registers (each thread's ep3 cells == its ep1 cells).
__global__ __launch_bounds__(512, 4) void k_postattn(
    const ushort* __restrict__ o, const ushort* __restrict__ qn,
    const ushort* __restrict__ wo, const float* __restrict__ bo,
    const float* __restrict__ lns1, const float* __restrict__ lnb1,
    const ushort* __restrict__ w1, const float* __restrict__ b1,
    const ushort* __restrict__ w2, const float* __restrict__ b2,
    const float* __restrict__ lns2, const float* __restrict__ lnb2,
    const int* __restrict__ expert_ids,
    ushort* __restrict__ seqs, ushort* __restrict__ qno) {
  int bid = blockIdx.x;
  int mt = bid % MT;
  int b  = bid / MT;
  int e = expert_ids[b];
  int m0 = mt * BM;
  int valid = min(BM, T - m0);
  size_t rowbase = (size_t)(b * T + m0);
  const ushort* Ob = o + rowbase * D;
  const ushort* We = wo + (size_t)e * D * D;

  __shared__ __align__(16) ushort U[BM * 256];    // 32K: O -> xn -> h
  __shared__ __align__(16) ushort Wl[D * BK];     // 32K: weight tile
  __shared__ float rs_sum[BM][4];
  __shared__ float rs_sq[BM][4];

  int tid = threadIdx.x, wv = tid >> 6, lane = tid & 63;
  int wr = wv >> 2, wc = wv & 3;
  int g = lane >> 4, lm = lane & 15;

  f32x4 acc[2][4];
  uint xnp[2][4][2];   // packed bf16 xn residual (static indexing only)
#pragma unroll
  for (int mi = 0; mi < 2; mi++)
#pragma unroll
    for (int ni = 0; ni < 4; ni++) {
      acc[mi][ni] = (f32x4){0.f, 0.f, 0.f, 0.f};
      xnp[mi][ni][0] = 0; xnp[mi][ni][1] = 0;
    }

  // prologue: O tile -> U (once)
  stage_full(Ob, D, valid, U, tid);
  __syncthreads();

  // ================= phase 1: oproj GEMM (A = U) ============================
  for (int kt = 0; kt < 4; kt++) {
    stage512<D>(We, D, D, kt * BK, Wl, tid);
    __syncthreads();
    bf16x8 a[2][2], bb[4][2];
#pragma unroll
    for (int mi = 0; mi < 2; mi++)
#pragma unroll
      for (int hh = 0; hh < 2; hh++)
        a[mi][hh] = frag256(U, wr * 32 + mi * 16 + lm, kt * BK, hh * 4 + g);
#pragma unroll
    for (int ni = 0; ni < 4; ni++)
#pragma unroll
      for (int hh = 0; hh < 2; hh++)
        bb[ni][hh] = frag(Wl, wc * 64 + ni * 16 + lm, hh * 4 + g);
#pragma unroll
    for (int mi = 0; mi < 2; mi++)
#pragma unroll
      for (int ni = 0; ni < 4; ni++) {
        acc[mi][ni] = __builtin_amdgcn_mfma_f32_16x16x32_bf16(a[mi][0], bb[ni][0],
                                                              acc[mi][ni], 0, 0, 0);
        acc[mi][ni] = __builtin_amdgcn_mfma_f32_16x16x32_bf16(a[mi][1], bb[ni][1],
                                                              acc[mi][ni], 0, 0, 0);
      }
    __syncthreads();
  }
  // epilogue 1: + bias + qn residual, row stats, fwd-LN -> xnp regs + U
#pragma unroll
  for (int ni = 0; ni < 4; ni++) {
    int col = wc * 64 + ni * 16 + lm;
    float bbv = bo[e * D + col];
#pragma unroll
    for (int mi = 0; mi < 2; mi++)
#pragma unroll
      for (int r = 0; r < 4; r++) {
        int lr = wr * 32 + mi * 16 + 4 * g + r;
        int lrc = (lr < valid) ? lr : (valid - 1);
        acc[mi][ni][r] += bbv + bf2f(qn[(rowbase + lrc) * D + col]);
      }
  }
#pragma unroll
  for (int mi = 0; mi < 2; mi++)
#pragma unroll
    for (int r = 0; r < 4; r++) {
      float s = 0.f, q2 = 0.f;
#pragma unroll
      for (int ni = 0; ni < 4; ni++) {
        float x = acc[mi][ni][r];
        s += x; q2 += x * x;
      }
#pragma unroll
      for (int off = 1; off < 16; off <<= 1) {
        s += __shfl_xor(s, off);
        q2 += __shfl_xor(q2, off);
      }
      if (lm == 0) {
        int row = wr * 32 + mi * 16 + 4 * g + r;
        rs_sum[row][wc] = s;
        rs_sq[row][wc] = q2;
      }
    }
  __syncthreads();
  {
    float scv[4], bcv[4];
#pragma unroll
    for (int ni = 0; ni < 4; ni++) {
      int col = wc * 64 + ni * 16 + lm;
      scv[ni] = lns1[col];
      bcv[ni] = lnb1[col];
    }
#pragma unroll
    for (int mi = 0; mi < 2; mi++)
#pragma unroll
      for (int r = 0; r < 4; r++) {
        int lr = wr * 32 + mi * 16 + 4 * g + r;
        float4 s4 = *(const float4*)rs_sum[lr];
        float4 q4 = *(const float4*)rs_sq[lr];
        float mean = (s4.x + s4.y + s4.z + s4.w) * (1.0f / D);
        float var = (q4.x + q4.y + q4.z + q4.w) * (1.0f / D) - mean * mean;
        float rstd = rsqrtf(fmaxf(var, 0.f) + 1e-8f);
#pragma unroll
        for (int ni = 0; ni < 4; ni++) {
          int col = wc * 64 + ni * 16 + lm;
          ushort us = f2bfs((acc[mi][ni][r] - mean) * rstd * scv[ni] + bcv[ni]);
          U[swz256(lr, col)] = us;                           // xn -> U (O dead)
          xnp[mi][ni][r >> 1] |= (uint)us << ((r & 1) * 16); // save for ep3
        }
      }
  }
  __syncthreads();   // xn visible to all waves

  // ================= phase 2: FFN1 (A = U = xn; h -> U) =====================
#pragma unroll
  for (int mi = 0; mi < 2; mi++)
#pragma unroll
    for (int ni = 0; ni < 4; ni++) acc[mi][ni] = (f32x4){0.f, 0.f, 0.f, 0.f};
  for (int kt = 0; kt < 4; kt++) {
    stage512<D>(w1, D, D, kt * BK, Wl, tid);
    __syncthreads();
    bf16x8 a[2][2], bb[4][2];
#pragma unroll
    for (int mi = 0; mi < 2; mi++)
#pragma unroll
      for (int hh = 0; hh < 2; hh++)
        a[mi][hh] = frag256(U, wr * 32 + mi * 16 + lm, kt * BK, hh * 4 + g);
#pragma unroll
    for (int ni = 0; ni < 4; ni++)
#pragma unroll
      for (int hh = 0; hh < 2; hh++)
        bb[ni][hh] = frag(Wl, wc * 64 + ni * 16 + lm, hh * 4 + g);
#pragma unroll
    for (int mi = 0; mi < 2; mi++)
#pragma unroll
      for (int ni = 0; ni < 4; ni++) {
        acc[mi][ni] = __builtin_amdgcn_mfma_f32_16x16x32_bf16(a[mi][0], bb[ni][0],
                                                              acc[mi][ni], 0, 0, 0);
        acc[mi][ni] = __builtin_amdgcn_mfma_f32_16x16x32_bf16(a[mi][1], bb[ni][1],
                                                              acc[mi][ni], 0, 0, 0);
      }
    __syncthreads();
  }
  // epilogue 2: h = relu(acc + b1) -> U (xn in U dead; kept in xnp)
#pragma unroll
  for (int ni = 0; ni < 4; ni++) {
    int col = wc * 64 + ni * 16 + lm;
    float bbv = b1[col];
#pragma unroll
    for (int mi = 0; mi < 2; mi++)
#pragma unroll
      for (int r = 0; r < 4; r++) {
        int row = wr * 32 + mi * 16 + 4 * g + r;
        U[swz256(row, col)] = f2bfs(fmaxf(acc[mi][ni][r] + bbv, 0.f));
      }
  }
  __syncthreads();   // h visible

  // ================= phase 3: FFN2 (A = U = h) ==============================
#pragma unroll
  for (int mi = 0; mi < 2; mi++)
#pragma unroll
    for (int ni = 0; ni < 4; ni++) acc[mi][ni] = (f32x4){0.f, 0.f, 0.f, 0.f};
  for (int kt = 0; kt < 4; kt++) {
    stage512<D>(w2, D, D, kt * BK, Wl, tid);
    __syncthreads();
    bf16x8 a[2][2], bb[4][2];
#pragma unroll
    for (int mi = 0; mi < 2; mi++)
#pragma unroll
      for (int hh = 0; hh < 2; hh++)
        a[mi][hh] = frag256(U, wr * 32 + mi * 16 + lm, kt * BK, hh * 4 + g);
#pragma unroll
    for (int ni = 0; ni < 4; ni++)
#pragma unroll
      for (int hh = 0; hh < 2; hh++)
        bb[ni][hh] = frag(Wl, wc * 64 + ni * 16 + lm, hh * 4 + g);
#pragma unroll
    for (int mi = 0; mi < 2; mi++)
#pragma unroll
      for (int ni = 0; ni < 4; ni++) {
        acc[mi][ni] = __builtin_amdgcn_mfma_f32_16x16x32_bf16(a[mi][0], bb[ni][0],
                                                              acc[mi][ni], 0, 0, 0);
        acc[mi][ni] = __builtin_amdgcn_mfma_f32_16x16x32_bf16(a[mi][1], bb[ni][1],
                                                              acc[mi][ni], 0, 0, 0);
      }
    __syncthreads();
  }
  // epilogue 3: + b2 + xn residual (from regs), row stats, next-layer attn-LN
#pragma unroll
  for (int ni = 0; ni < 4; ni++) {
    int col = wc * 64 + ni * 16 + lm;
    float bbv = b2[col];
#pragma unroll
    for (int mi = 0; mi < 2; mi++)
#pragma unroll
      for (int r = 0; r < 4; r++) {
        ushort us = (ushort)((xnp[mi][ni][r >> 1] >> ((r & 1) * 16)) & 0xffffu);
        acc[mi][ni][r] += bbv + bf2f(us);
      }
  }
#pragma unroll
  for (int mi = 0; mi < 2; mi++)
#pragma unroll
    for (int r = 0; r < 4; r++) {
      float s = 0.f, q2 = 0.f;
#pragma unroll
      for (int ni = 0; ni < 4; ni++) {
        float x = acc[mi][ni][r];
        s += x; q2 += x * x;
      }
#pragma unroll
      for (int off = 1; off < 16; off <<= 1) {
        s += __shfl_xor(s, off);
        q2 += __shfl_xor(q2, off);
      }
      if (lm == 0) {
        int row = wr * 32 + mi * 16 + 4 * g + r;
        rs_sum[row][wc] = s;
        rs_sq[row][wc] = q2;
      }
    }
  __syncthreads();
  {
    float scv[4], bcv[4];
#pragma unroll
    for (int ni = 0; ni < 4; ni++) {
      int col = wc * 64 + ni * 16 + lm;
      scv[ni] = lns2[col];
      bcv[ni] = lnb2[col];
    }
#pragma unroll
    for (int mi = 0; mi < 2; mi++)
#pragma unroll
      for (int r = 0; r < 4; r++) {
        int lr = wr * 32 + mi * 16 + 4 * g + r;
        float4 s4 = *(const float4*)rs_sum[lr];
        float4 q4 = *(const float4*)rs_sq[lr];
        float mean = (s4.x + s4.y + s4.z + s4.w) * (1.0f / D);
        float var = (q4.x + q4.y + q4.z + q4.w) * (1.0f / D) - mean * mean;
        float rstd = rsqrtf(fmaxf(var, 0.f) + 1e-8f);
        if (lr < valid) {
#pragma unroll
          for (int ni = 0; ni < 4; ni++) {
            int col = wc * 64 + ni * 16 + lm;
            float val = acc[mi][ni][r];
            size_t idx = (rowbase + lr) * D + col;
            seqs[idx] = f2bfs(val);
            qno[idx] = f2bfs((val - mean) * rstd * scv[ni] + bcv[ni]);
          }
        }
      }
  }
}

// ---------------- MFMA flash attention (bf16 io) -----------------------------
constexpr int KROWS = 224;
constexpr int KSS = 72;
constexpr int VSS = 232;
constexpr int PSS = 40;
__global__ __launch_bounds__(256) void k_attn(const ushort* __restrict__ q,
                                              const ushort* __restrict__ k,
                                              const ushort* __restrict__ v,
                                              ushort* __restrict__ o) {
  int bh = blockIdx.x;
  int b = bh >> 2, h = bh & 3;
  __shared__ __align__(16) ushort Kl[KROWS][KSS];
  __shared__ __align__(16) ushort Vt[HD][VSS];
  __shared__ __align__(16) ushort Pl[4][16][PSS];
  const size_t base = (size_t)b * T * D + h * HD;
  int tid = threadIdx.x, wave = tid >> 6, lane = tid & 63;
  int g = lane >> 4, lm = lane & 15;

#pragma unroll
  for (int p = 0; p < 7; p++) {
    int slot = p * 256 + tid;
    int key = slot >> 3, s8 = (slot & 7) << 3;
    uint4 w = make_uint4(0, 0, 0, 0);
    if (key < T) w = *(const uint4*)(k + base + (size_t)key * D + s8);
    *(uint4*)&Kl[key][s8] = w;
  }
#pragma unroll
  for (int p = 0; p < 28; p++) {
    int slot = p * 256 + tid;
    int key = slot >> 5, dp = (slot & 31) << 1;
    unsigned int w = 0;
    if (key < T) w = *(const unsigned int*)(v + base + (size_t)key * D + dp);
    Vt[dp][key] = (ushort)(w & 0xffffu);
    Vt[dp + 1][key] = (ushort)(w >> 16);
  }
  __syncthreads();

  const unsigned long long SCHED = 0x0189D27AD36BD45CULL;
  unsigned sch = (unsigned)(SCHED >> (wave * 16)) & 0xFFFFu;
  const float sc = 0.125f * 1.44269504f;

  for (int si = 0; si < 4; si++) {
    int qt = (sch >> (si * 4)) & 15;
    if (qt > 12) break;
    int row = qt * 16 + lm;
    int qrow = min(row, T - 1);
    const ushort* qr = q + base + (size_t)qrow * D;
    bf16x8 qf0 = ldb8(qr + 8 * g);
    bf16x8 qf1 = ldb8(qr + 32 + 8 * g);

    f32x4 oacc[4];
#pragma unroll
    for (int dt = 0; dt < 4; dt++) oacc[dt] = (f32x4){0.f, 0.f, 0.f, 0.f};
    float mrun = -3e38f, lsum = 0.f;

    int nch = qt / 2 + 1;
    for (int c = 0; c < nch; c++) {
      int kb = c * 32;
      f32x4 s01[2];
#pragma unroll
      for (int t = 0; t < 2; t++) {
        int krow = kb + t * 16 + lm;
        bf16x8 a0 = ldb8(&Kl[krow][8 * g]);
        bf16x8 a1 = ldb8(&Kl[krow][32 + 8 * g]);
        f32x4 z = (f32x4){0.f, 0.f, 0.f, 0.f};
        z = __builtin_amdgcn_mfma_f32_16x16x32_bf16(a0, qf0, z, 0, 0, 0);
        z = __builtin_amdgcn_mfma_f32_16x16x32_bf16(a1, qf1, z, 0, 0, 0);
        s01[t] = z;
      }
      float sv[8];
      float mx = -3e38f;
#pragma unroll
      for (int t = 0; t < 2; t++)
#pragma unroll
        for (int r = 0; r < 4; r++) {
          int key = kb + t * 16 + 4 * g + r;
          float x = (key <= row) ? s01[t][r] * sc : -3e38f;
          sv[t * 4 + r] = x;
          mx = fmaxf(mx, x);
        }
      mx = fmaxf(mx, __shfl_xor(mx, 16));
      mx = fmaxf(mx, __shfl_xor(mx, 32));
      float mnew = fmaxf(mrun, mx);
      float corr = __builtin_amdgcn_exp2f(mrun - mnew);
      float ps = 0.f;
      ushort8v pu;
#pragma unroll
      for (int i = 0; i < 8; i++) {
        float p = __builtin_amdgcn_exp2f(sv[i] - mnew);
        ps += p;
        pu[i] = f2bfs(p);
      }
      ps += __shfl_xor(ps, 16);
      ps += __shfl_xor(ps, 32);
      lsum = lsum * corr + ps;
      mrun = mnew;
      *(ushort4*)&Pl[wave][lm][4 * g]      = ((ushort4*)&pu)[0];
      *(ushort4*)&Pl[wave][lm][16 + 4 * g] = ((ushort4*)&pu)[1];
#pragma unroll
      for (int dt = 0; dt < 4; dt++)
#pragma unroll
        for (int r = 0; r < 4; r++) oacc[dt][r] *= corr;
      bf16x8 pf = ldb8(&Pl[wave][lm][8 * g]);
#pragma unroll
      for (int dt = 0; dt < 4; dt++) {
        bf16x8 av = ldb8(&Vt[dt * 16 + lm][kb + 8 * g]);
        oacc[dt] = __builtin_amdgcn_mfma_f32_16x16x32_bf16(av, pf, oacc[dt], 0, 0, 0);
      }
    }

    if (row < T) {
      float rinv = 1.0f / lsum;
      ushort* orow = o + base + (size_t)row * D;
#pragma unroll
      for (int dt = 0; dt < 4; dt++) {
        ushort4 uo;
        uo.x = f2bfs(oacc[dt][0] * rinv);
        uo.y = f2bfs(oacc[dt][1] * rinv);
        uo.z = f2bfs(oacc[dt][2] * rinv);
        uo.w = f2bfs(oacc[dt][3] * rinv);
        *(ushort4*)(orow + dt * 16 + 4 * g) = uo;
      }
    }
  }
}

// ---------------- final LN + pos/neg logits ----------------------------------
__global__ __launch_bounds__(256) void k_final(const ushort* __restrict__ seqs,
                                               const float* __restrict__ sc,
                                               const float* __restrict__ bi,
                                               const int* __restrict__ pos_seqs,
                                               const int* __restrict__ neg_seqs,
                                               const float* __restrict__ item_emb,
                                               float* __restrict__ out) {
  int tok = blockIdx.x * 4 + (threadIdx.x >> 6);
  int lane = threadIdx.x & 63;
  ushort4 xu = ((const ushort4*)(seqs + (size_t)tok * D))[lane];
  float x0 = bf2f(xu.x), x1 = bf2f(xu.y), x2 = bf2f(xu.z), x3 = bf2f(xu.w);
  float mean = wave_sum(x0 + x1 + x2 + x3) * (1.0f / D);
  float c0 = x0 - mean, c1 = x1 - mean, c2 = x2 - mean, c3 = x3 - mean;
  float var = wave_sum(c0 * c0 + c1 * c1 + c2 * c2 + c3 * c3) * (1.0f / D);
  float inv = rsqrtf(var + 1e-8f);
  float4 sv = ((const float4*)sc)[lane];
  float4 bv = ((const float4*)bi)[lane];
  float f0 = c0 * inv * sv.x + bv.x;
  float f1 = c1 * inv * sv.y + bv.y;
  float f2 = c2 * inv * sv.z + bv.z;
  float f3 = c3 * inv * sv.w + bv.w;
  int ip = pos_seqs[tok];
  int in_ = neg_seqs[tok];
  float4 pe = ((const float4*)(item_emb + (size_t)ip * D))[lane];
  float4 ne = ((const float4*)(item_emb + (size_t)in_ * D))[lane];
  float dp = wave_sum(f0 * pe.x + f1 * pe.y + f2 * pe.z + f3 * pe.w);
  float dn = wave_sum(f0 * ne.x + f1 * ne.y + f2 * ne.z + f3 * ne.w);
  if (lane == 0) {
    out[tok] = dp;
    out[BT + tok] = dn;
  }
}

}  // namespace

extern "C" void kernel_launch(void* const* d_in, const int* in_sizes, int n_in,
                              void* d_out, int out_size, void* d_ws, size_t ws_size,
                              hipStream_t stream) {
  const int*   log_seqs   = (const int*)d_in[0];
  const int*   pos_seqs   = (const int*)d_in[1];
  const int*   neg_seqs   = (const int*)d_in[2];
  const int*   expert_ids = (const int*)d_in[3];
  const float* item_emb   = (const float*)d_in[4];
  const float* pos_emb    = (const float*)d_in[5];
  const float* attn_ln_s  = (const float*)d_in[6];
  const float* attn_ln_b  = (const float*)d_in[7];
  const float* in_w       = (const float*)d_in[8];
  const float* in_b       = (const float*)d_in[9];
  const float* out_w      = (const float*)d_in[10];
  const float* out_b      = (const float*)d_in[11];
  const float* fwd_ln_s   = (const float*)d_in[12];
  const float* fwd_ln_b   = (const float*)d_in[13];
  const float* ffn_w1     = (const float*)d_in[14];
  const float* ffn_b1     = (const float*)d_in[15];
  const float* ffn_w2     = (const float*)d_in[16];
  const float* ffn_b2     = (const float*)d_in[17];
  const float* last_ln_s  = (const float*)d_in[18];
  const float* last_ln_b  = (const float*)d_in[19];
  float* out = (float*)d_out;

  const size_t N = (size_t)BT * D;
  ushort* seqs = (ushort*)d_ws;
  ushort* qn   = seqs + N;
  ushort* q    = qn + N;
  ushort* kbuf = q + N;
  ushort* vbuf = kbuf + N;
  ushort* obuf = kbuf;   // alias: attn stages K to LDS before writing o
  ushort* wqkv = vbuf + N;                               // [NL][NE][3D][D]
  ushort* wout = wqkv + (size_t)NL * NE * 3 * D * D;     // [NL][NE][D][D]
  ushort* wf1  = wout + (size_t)NL * NE * D * D;         // [NL][D][D]
  ushort* wf2  = wf1 + (size_t)NL * D * D;               // [NL][D][D]

  {
    int nA4 = NL * NE * 3 * D * D / 4;
    int nB4 = NL * NE * D * D / 4;
    int nC4 = NL * D * D / 4;
    int tot = nA4 + nB4 + 2 * nC4;
    k_cvt_all<<<(tot + 255) / 256, 256, 0, stream>>>(in_w, out_w, ffn_w1, ffn_w2,
                                                     wqkv, nA4, nB4, nC4);
  }

  k_embed_ln<<<BT / 4, 256, 0, stream>>>(log_seqs, item_emb, pos_emb,
                                         attn_ln_s, attn_ln_b, seqs, qn);

  for (int l = 0; l < NL; l++) {
    int ln_next = (l + 1 < NL) ? (l + 1) : l;   // last-layer qn write unused
    k_gemm_qkv<<<B * MT * 6, 256, 0, stream>>>(
        qn, seqs, wqkv + (size_t)l * NE * 3 * D * D,
        in_b + (size_t)l * NE * 3 * D, expert_ids, q, kbuf, vbuf);
    k_attn<<<B * H, 256, 0, stream>>>(q, kbuf, vbuf, obuf);
    k_postattn<<<B * MT, 512, 0, stream>>>(
        obuf, qn, wout + (size_t)l * NE * D * D, out_b + (size_t)l * NE * D,
        fwd_ln_s + (size_t)l * D, fwd_ln_b + (size_t)l * D,
        wf1 + (size_t)l * D * D, ffn_b1 + (size_t)l * D,
        wf2 + (size_t)l * D * D, ffn_b2 + (size_t)l * D,
        attn_ln_s + (size_t)ln_next * D, attn_ln_b + (size_t)ln_next * D,
        expert_ids, seqs, qn);
  }

  k_final<<<BT / 4, 256, 0, stream>>>(seqs, last_ln_s, last_ln_b, pos_seqs,
                                      neg_seqs, item_emb, out);
}